// Round 1
// baseline (1422.851 us; speedup 1.0000x reference)
//
#include <hip/hip_runtime.h>
#include <math.h>

#define NN 100000
#define NE 1600000
#define D 64

// ---------------- Kernel 1: out[n][d] = bias[d] ----------------
__global__ __launch_bounds__(256) void init_out_kernel(float* __restrict__ out,
                                                       const float* __restrict__ bias,
                                                       int n_f4) {
    int i = blockIdx.x * blockDim.x + threadIdx.x;
    if (i >= n_f4) return;
    // 16 float4 per row of 64
    float4 b4 = reinterpret_cast<const float4*>(bias)[i & 15];
    reinterpret_cast<float4*>(out)[i] = b4;
}

// ---------------- Kernel 2: xt = x @ W  ([NN,64] @ [64,64]) ----------------
// One 64-lane wave per row; lane d owns output column d, holds W[:,d] in regs.
__global__ __launch_bounds__(256) void xt_gemm_kernel(const float* __restrict__ x,
                                                      const float* __restrict__ W,
                                                      float* __restrict__ xt,
                                                      int n_nodes) {
    const int d = threadIdx.x & 63;
    const int wave_in_block = threadIdx.x >> 6;       // 0..3
    const int waves_total = gridDim.x * 4;
    const int wid = blockIdx.x * 4 + wave_in_block;

    float wcol[64];
#pragma unroll
    for (int k = 0; k < 64; ++k) wcol[k] = W[k * 64 + d];

    for (int row = wid; row < n_nodes; row += waves_total) {
        const float4* xr = reinterpret_cast<const float4*>(x + (size_t)row * 64);
        float acc = 0.f;
#pragma unroll
        for (int kk = 0; kk < 16; ++kk) {
            float4 xv = xr[kk];
            acc += xv.x * wcol[4 * kk + 0];
            acc += xv.y * wcol[4 * kk + 1];
            acc += xv.z * wcol[4 * kk + 2];
            acc += xv.w * wcol[4 * kk + 3];
        }
        xt[(size_t)row * 64 + d] = acc;
    }
}

// ---------------- Kernel 3: edge gather-multiply-scatter ----------------
// 16 lanes per edge; lane l handles d = 4l..4l+3 as float4.
// msg = xt[src] * sigmoid(ea * ewW + ewb); atomicAdd into out[dst].
__global__ __launch_bounds__(256) void edge_kernel(const int* __restrict__ ei,
                                                   const float* __restrict__ ea,
                                                   const float* __restrict__ xt,
                                                   const float* __restrict__ ewW,
                                                   const float* __restrict__ ewb,
                                                   float* __restrict__ out,
                                                   int n_edges) {
    __shared__ float sW[64];
    __shared__ float sb[64];
    if (threadIdx.x < 64) {
        sW[threadIdx.x] = ewW[threadIdx.x];
        sb[threadIdx.x] = ewb[threadIdx.x];
    }
    __syncthreads();

    const int gid = blockIdx.x * blockDim.x + threadIdx.x;
    const int lane4 = gid & 15;            // which float4 chunk of the 64-d row
    const int d0 = lane4 * 4;
    int e = gid >> 4;
    const int estride = (gridDim.x * blockDim.x) >> 4;

    for (; e < n_edges; e += estride) {
        const int src = ei[e];
        const int dst = ei[n_edges + e];
        const float a = ea[e];

        float4 xv = *reinterpret_cast<const float4*>(xt + (size_t)src * 64 + d0);

        float t0 = a * sW[d0 + 0] + sb[d0 + 0];
        float t1 = a * sW[d0 + 1] + sb[d0 + 1];
        float t2 = a * sW[d0 + 2] + sb[d0 + 2];
        float t3 = a * sW[d0 + 3] + sb[d0 + 3];
        float w0 = 1.f / (1.f + __expf(-t0));
        float w1 = 1.f / (1.f + __expf(-t1));
        float w2 = 1.f / (1.f + __expf(-t2));
        float w3 = 1.f / (1.f + __expf(-t3));

        float* op = out + (size_t)dst * 64 + d0;
        unsafeAtomicAdd(op + 0, xv.x * w0);
        unsafeAtomicAdd(op + 1, xv.y * w1);
        unsafeAtomicAdd(op + 2, xv.z * w2);
        unsafeAtomicAdd(op + 3, xv.w * w3);
    }
}

extern "C" void kernel_launch(void* const* d_in, const int* in_sizes, int n_in,
                              void* d_out, int out_size, void* d_ws, size_t ws_size,
                              hipStream_t stream) {
    const float* x      = (const float*)d_in[0];
    const int*   ei     = (const int*)d_in[1];
    const float* ea     = (const float*)d_in[2];
    const float* weight = (const float*)d_in[3];
    const float* ewW    = (const float*)d_in[4];
    const float* ewb    = (const float*)d_in[5];
    float* out = (float*)d_out;
    float* xt  = (float*)d_ws;   // 100000*64*4 = 25.6 MB scratch

    const int n_nodes = in_sizes[0] / D;      // 100000
    const int n_edges = in_sizes[2];          // 1600000 (edge_attr has EDGE_DIM=1)

    // 1) out = bias (broadcast)
    {
        int n_f4 = n_nodes * (D / 4);
        int blk = 256;
        int grid = (n_f4 + blk - 1) / blk;
        init_out_kernel<<<grid, blk, 0, stream>>>(out, (const float*)d_in[6], n_f4);
    }
    // 2) xt = x @ W
    {
        int grid = 1024;  // 4096 waves, ~25 rows each
        xt_gemm_kernel<<<grid, 256, 0, stream>>>(x, weight, xt, n_nodes);
    }
    // 3) edge scatter
    {
        int grid = 4096;  // 1M threads = 64K edge slots, ~25 edges each
        edge_kernel<<<grid, 256, 0, stream>>>(ei, ea, xt, ewW, ewb, out, n_edges);
    }
}

// Round 2
// 341.833 us; speedup vs baseline: 4.1624x; 4.1624x over previous
//
#include <hip/hip_runtime.h>
#include <math.h>

#define D 64
#define SCAN_B 256

// ---------------- xt = x @ W  ([N,64] @ [64,64]) ----------------
// One 64-lane wave per row; lane d owns output column d, holds W[:,d] in regs.
__global__ __launch_bounds__(256) void xt_gemm_kernel(const float* __restrict__ x,
                                                      const float* __restrict__ W,
                                                      float* __restrict__ xt,
                                                      int n_nodes) {
    const int d = threadIdx.x & 63;
    const int wave_in_block = threadIdx.x >> 6;
    const int waves_total = gridDim.x * 4;
    const int wid = blockIdx.x * 4 + wave_in_block;

    float wcol[64];
#pragma unroll
    for (int k = 0; k < 64; ++k) wcol[k] = W[k * 64 + d];

    for (int row = wid; row < n_nodes; row += waves_total) {
        const float4* xr = reinterpret_cast<const float4*>(x + (size_t)row * 64);
        float acc = 0.f;
#pragma unroll
        for (int kk = 0; kk < 16; ++kk) {
            float4 xv = xr[kk];
            acc += xv.x * wcol[4 * kk + 0];
            acc += xv.y * wcol[4 * kk + 1];
            acc += xv.z * wcol[4 * kk + 2];
            acc += xv.w * wcol[4 * kk + 3];
        }
        xt[(size_t)row * 64 + d] = acc;
    }
}

// ---------------- CSR build: count -> scan -> fill ----------------
__global__ __launch_bounds__(256) void count_kernel(const int* __restrict__ ei,
                                                    int* __restrict__ counts,
                                                    int n_edges) {
    int i = blockIdx.x * blockDim.x + threadIdx.x;
    if (i < n_edges) atomicAdd(&counts[ei[n_edges + i]], 1);
}

// block-level inclusive scan -> exclusive per element + block totals
__global__ __launch_bounds__(SCAN_B) void scan1_kernel(const int* __restrict__ c,
                                                       int* __restrict__ excl,
                                                       int* __restrict__ partials,
                                                       int n) {
    __shared__ int s[SCAN_B];
    int i = blockIdx.x * SCAN_B + threadIdx.x;
    int v = (i < n) ? c[i] : 0;
    s[threadIdx.x] = v;
    __syncthreads();
    for (int off = 1; off < SCAN_B; off <<= 1) {
        int t = (threadIdx.x >= off) ? s[threadIdx.x - off] : 0;
        __syncthreads();
        s[threadIdx.x] += t;
        __syncthreads();
    }
    if (i < n) excl[i] = s[threadIdx.x] - v;
    if (threadIdx.x == SCAN_B - 1) partials[blockIdx.x] = s[SCAN_B - 1];
}

__global__ __launch_bounds__(512) void scan2_kernel(int* __restrict__ partials, int nb) {
    __shared__ int s[512];
    int v = (threadIdx.x < (unsigned)nb) ? partials[threadIdx.x] : 0;
    s[threadIdx.x] = v;
    __syncthreads();
    for (int off = 1; off < 512; off <<= 1) {
        int t = (threadIdx.x >= off) ? s[threadIdx.x - off] : 0;
        __syncthreads();
        s[threadIdx.x] += t;
        __syncthreads();
    }
    if (threadIdx.x < (unsigned)nb) partials[threadIdx.x] = s[threadIdx.x] - v;
}

__global__ __launch_bounds__(SCAN_B) void scan3_kernel(int* __restrict__ offsets,
                                                       int* __restrict__ cursor,
                                                       const int* __restrict__ partials,
                                                       int n, int n_edges) {
    int i = blockIdx.x * SCAN_B + threadIdx.x;
    if (i < n) {
        int o = offsets[i] + partials[blockIdx.x];
        offsets[i] = o;
        cursor[i] = o;
    }
    if (i == 0) offsets[n] = n_edges;
}

__global__ __launch_bounds__(256) void fill_kernel(const int* __restrict__ ei,
                                                   const float* __restrict__ ea,
                                                   int* __restrict__ cursor,
                                                   int2* __restrict__ csr,
                                                   int n_edges) {
    int i = blockIdx.x * blockDim.x + threadIdx.x;
    if (i < n_edges) {
        int dst = ei[n_edges + i];
        int pos = atomicAdd(&cursor[dst], 1);
        csr[pos] = make_int2(ei[i], __float_as_int(ea[i]));
    }
}

// ---------------- gather: one wave per node, lane = dim ----------------
__global__ __launch_bounds__(256) void gather_kernel(const int* __restrict__ offsets,
                                                     const int2* __restrict__ csr,
                                                     const float* __restrict__ xt,
                                                     const float* __restrict__ ewW,
                                                     const float* __restrict__ ewb,
                                                     const float* __restrict__ bias,
                                                     float* __restrict__ out,
                                                     int n_nodes) {
    const int d = threadIdx.x & 63;
    const int node = blockIdx.x * 4 + (threadIdx.x >> 6);
    if (node >= n_nodes) return;

    const float wd = ewW[d];
    const float bd = ewb[d];
    const int start = offsets[node];
    const int end = offsets[node + 1];

    float acc = 0.f;
    int k = start;
    // 2-wide to break the csr->xt dependent-load chain
    for (; k + 2 <= end; k += 2) {
        int2 p0 = csr[k];
        int2 p1 = csr[k + 1];
        float x0 = xt[(size_t)p0.x * 64 + d];
        float x1 = xt[(size_t)p1.x * 64 + d];
        float a0 = __int_as_float(p0.y);
        float a1 = __int_as_float(p1.y);
        float w0 = 1.f / (1.f + __expf(-(a0 * wd + bd)));
        float w1 = 1.f / (1.f + __expf(-(a1 * wd + bd)));
        acc += x0 * w0;
        acc += x1 * w1;
    }
    if (k < end) {
        int2 p = csr[k];
        float xv = xt[(size_t)p.x * 64 + d];
        float a = __int_as_float(p.y);
        float w = 1.f / (1.f + __expf(-(a * wd + bd)));
        acc += xv * w;
    }
    out[(size_t)node * 64 + d] = acc + bias[d];
}

// ---------------- fallback (round-1 path) ----------------
__global__ __launch_bounds__(256) void init_out_kernel(float* __restrict__ out,
                                                       const float* __restrict__ bias,
                                                       int n_f4) {
    int i = blockIdx.x * blockDim.x + threadIdx.x;
    if (i >= n_f4) return;
    float4 b4 = reinterpret_cast<const float4*>(bias)[i & 15];
    reinterpret_cast<float4*>(out)[i] = b4;
}

__global__ __launch_bounds__(256) void edge_atomic_kernel(const int* __restrict__ ei,
                                                          const float* __restrict__ ea,
                                                          const float* __restrict__ xt,
                                                          const float* __restrict__ ewW,
                                                          const float* __restrict__ ewb,
                                                          float* __restrict__ out,
                                                          int n_edges) {
    const int gid = blockIdx.x * blockDim.x + threadIdx.x;
    const int d0 = (gid & 15) * 4;
    int e = gid >> 4;
    const int estride = (gridDim.x * blockDim.x) >> 4;
    for (; e < n_edges; e += estride) {
        const int src = ei[e];
        const int dst = ei[n_edges + e];
        const float a = ea[e];
        float4 xv = *reinterpret_cast<const float4*>(xt + (size_t)src * 64 + d0);
        float w0 = 1.f / (1.f + __expf(-(a * ewW[d0 + 0] + ewb[d0 + 0])));
        float w1 = 1.f / (1.f + __expf(-(a * ewW[d0 + 1] + ewb[d0 + 1])));
        float w2 = 1.f / (1.f + __expf(-(a * ewW[d0 + 2] + ewb[d0 + 2])));
        float w3 = 1.f / (1.f + __expf(-(a * ewW[d0 + 3] + ewb[d0 + 3])));
        float* op = out + (size_t)dst * 64 + d0;
        unsafeAtomicAdd(op + 0, xv.x * w0);
        unsafeAtomicAdd(op + 1, xv.y * w1);
        unsafeAtomicAdd(op + 2, xv.z * w2);
        unsafeAtomicAdd(op + 3, xv.w * w3);
    }
}

extern "C" void kernel_launch(void* const* d_in, const int* in_sizes, int n_in,
                              void* d_out, int out_size, void* d_ws, size_t ws_size,
                              hipStream_t stream) {
    const float* x      = (const float*)d_in[0];
    const int*   ei     = (const int*)d_in[1];
    const float* ea     = (const float*)d_in[2];
    const float* weight = (const float*)d_in[3];
    const float* ewW    = (const float*)d_in[4];
    const float* ewb    = (const float*)d_in[5];
    const float* bias   = (const float*)d_in[6];
    float* out = (float*)d_out;

    const int n_nodes = in_sizes[0] / D;   // 100000
    const int n_edges = in_sizes[2];       // 1600000

    // workspace layout (bytes)
    char* ws = (char*)d_ws;
    const size_t xt_off      = 0;
    const size_t xt_bytes    = (size_t)n_nodes * D * sizeof(float);          // 25.6 MB
    const size_t off_off     = xt_off + xt_bytes;
    const size_t off_bytes   = ((size_t)n_nodes + 1 + 3) / 4 * 4 * sizeof(int);
    const size_t cur_off     = off_off + off_bytes;
    const size_t cur_bytes   = off_bytes;
    const size_t part_off    = cur_off + cur_bytes;
    const size_t part_bytes  = 512 * sizeof(int);
    size_t csr_off           = part_off + part_bytes;
    csr_off = (csr_off + 7) & ~(size_t)7;
    const size_t csr_bytes   = (size_t)n_edges * sizeof(int2);               // 12.8 MB
    const size_t need        = csr_off + csr_bytes;

    float* xt     = (float*)(ws + xt_off);
    int*   offs   = (int*)(ws + off_off);
    int*   cursor = (int*)(ws + cur_off);
    int*   parts  = (int*)(ws + part_off);
    int2*  csr    = (int2*)(ws + csr_off);

    // xt = x @ W (needed by both paths)
    xt_gemm_kernel<<<1024, 256, 0, stream>>>(x, weight, xt, n_nodes);

    if (ws_size < need) {
        // fallback: atomic scatter path
        int n_f4 = n_nodes * (D / 4);
        init_out_kernel<<<(n_f4 + 255) / 256, 256, 0, stream>>>(out, bias, n_f4);
        edge_atomic_kernel<<<4096, 256, 0, stream>>>(ei, ea, xt, ewW, ewb, out, n_edges);
        return;
    }

    const int nscan_blocks = (n_nodes + SCAN_B - 1) / SCAN_B;   // 391 (<=512)

    // counts := 0 (reuse offs buffer as counts)
    hipMemsetAsync(offs, 0, off_bytes, stream);
    count_kernel<<<(n_edges + 255) / 256, 256, 0, stream>>>(ei, offs, n_edges);
    scan1_kernel<<<nscan_blocks, SCAN_B, 0, stream>>>(offs, offs, parts, n_nodes);
    scan2_kernel<<<1, 512, 0, stream>>>(parts, nscan_blocks);
    scan3_kernel<<<nscan_blocks, SCAN_B, 0, stream>>>(offs, cursor, parts, n_nodes, n_edges);
    fill_kernel<<<(n_edges + 255) / 256, 256, 0, stream>>>(ei, ea, cursor, csr, n_edges);

    gather_kernel<<<(n_nodes + 3) / 4, 256, 0, stream>>>(offs, csr, xt, ewW, ewb, bias, out, n_nodes);
}

// Round 3
// 328.736 us; speedup vs baseline: 4.3283x; 1.0398x over previous
//
#include <hip/hip_runtime.h>
#include <hip/hip_bf16.h>
#include <math.h>

#define D 64
#define SCAN_B 256

typedef __hip_bfloat16 bf16;

// ---------- K1: fused dst-histogram + xt = x @ W (bf16 out) ----------
// Count atomics are fire-and-forget (no return value -> no wait); their
// latency hides under the 64-FMA/row GEMM work.
__global__ __launch_bounds__(256) void gemm_count_kernel(
    const float* __restrict__ x, const float* __restrict__ W,
    const int* __restrict__ ei,
    bf16* __restrict__ xt, int* __restrict__ counts,
    int n_nodes, int n_edges)
{
    const int gid = blockIdx.x * blockDim.x + threadIdx.x;
    const int nth = gridDim.x * blockDim.x;

    // phase A: histogram of dst
    for (int e = gid; e < n_edges; e += nth)
        atomicAdd(&counts[ei[n_edges + e]], 1);

    // phase B: one wave per row, lane d owns output column d
    const int d = threadIdx.x & 63;
    const int wid = gid >> 6;
    const int waves_total = nth >> 6;

    float wcol[64];
#pragma unroll
    for (int k = 0; k < 64; ++k) wcol[k] = W[k * 64 + d];

    for (int row = wid; row < n_nodes; row += waves_total) {
        const float4* xr = reinterpret_cast<const float4*>(x + (size_t)row * 64);
        float acc = 0.f;
#pragma unroll
        for (int kk = 0; kk < 16; ++kk) {
            float4 xv = xr[kk];
            acc = fmaf(xv.x, wcol[4 * kk + 0], acc);
            acc = fmaf(xv.y, wcol[4 * kk + 1], acc);
            acc = fmaf(xv.z, wcol[4 * kk + 2], acc);
            acc = fmaf(xv.w, wcol[4 * kk + 3], acc);
        }
        xt[(size_t)row * 64 + d] = __float2bfloat16(acc);
    }
}

// ---------- K2: block scan (exclusive) + block totals ----------
__global__ __launch_bounds__(SCAN_B) void scan1_kernel(const int* __restrict__ c,
                                                       int* __restrict__ excl,
                                                       int* __restrict__ partials,
                                                       int n) {
    __shared__ int s[SCAN_B];
    int i = blockIdx.x * SCAN_B + threadIdx.x;
    int v = (i < n) ? c[i] : 0;
    s[threadIdx.x] = v;
    __syncthreads();
    for (int off = 1; off < SCAN_B; off <<= 1) {
        int t = (threadIdx.x >= off) ? s[threadIdx.x - off] : 0;
        __syncthreads();
        s[threadIdx.x] += t;
        __syncthreads();
    }
    if (i < n) excl[i] = s[threadIdx.x] - v;
    if (threadIdx.x == SCAN_B - 1) partials[blockIdx.x] = s[SCAN_B - 1];
}

// ---------- K3: apply partials prefix (each block reduces its own prefix) ----------
__global__ __launch_bounds__(SCAN_B) void scan23_kernel(int* __restrict__ offsets,
                                                        int* __restrict__ cursor,
                                                        const int* __restrict__ partials,
                                                        int n, int n_edges) {
    __shared__ int red[SCAN_B];
    int psum = 0;
    for (int i = threadIdx.x; i < blockIdx.x; i += SCAN_B) psum += partials[i];
    red[threadIdx.x] = psum;
    __syncthreads();
    for (int off = SCAN_B / 2; off > 0; off >>= 1) {
        if (threadIdx.x < off) red[threadIdx.x] += red[threadIdx.x + off];
        __syncthreads();
    }
    int base = red[0];
    int i = blockIdx.x * SCAN_B + threadIdx.x;
    if (i < n) {
        int o = offsets[i] + base;
        offsets[i] = o;
        cursor[i] = o;
    }
    if (blockIdx.x == 0 && threadIdx.x == 0) offsets[n] = n_edges;
}

// ---------- K4: CSR fill, 4 edges/thread (4 independent atomic->store chains) ----------
__global__ __launch_bounds__(256) void fill_kernel(const int* __restrict__ ei,
                                                   const float* __restrict__ ea,
                                                   int* __restrict__ cursor,
                                                   int2* __restrict__ csr,
                                                   int n_edges) {
    const int i0 = (blockIdx.x * blockDim.x + threadIdx.x) * 4;
    if (i0 + 4 <= n_edges) {
        int d0 = ei[n_edges + i0 + 0];
        int d1 = ei[n_edges + i0 + 1];
        int d2 = ei[n_edges + i0 + 2];
        int d3 = ei[n_edges + i0 + 3];
        int s0 = ei[i0 + 0], s1 = ei[i0 + 1], s2 = ei[i0 + 2], s3 = ei[i0 + 3];
        float a0 = ea[i0 + 0], a1 = ea[i0 + 1], a2 = ea[i0 + 2], a3 = ea[i0 + 3];
        int p0 = atomicAdd(&cursor[d0], 1);
        int p1 = atomicAdd(&cursor[d1], 1);
        int p2 = atomicAdd(&cursor[d2], 1);
        int p3 = atomicAdd(&cursor[d3], 1);
        long long v0 = ((long long)__float_as_int(a0) << 32) | (unsigned)s0;
        long long v1 = ((long long)__float_as_int(a1) << 32) | (unsigned)s1;
        long long v2 = ((long long)__float_as_int(a2) << 32) | (unsigned)s2;
        long long v3 = ((long long)__float_as_int(a3) << 32) | (unsigned)s3;
        __builtin_nontemporal_store(v0, (long long*)(csr + p0));
        __builtin_nontemporal_store(v1, (long long*)(csr + p1));
        __builtin_nontemporal_store(v2, (long long*)(csr + p2));
        __builtin_nontemporal_store(v3, (long long*)(csr + p3));
    } else {
        for (int i = i0; i < n_edges; ++i) {
            int dst = ei[n_edges + i];
            int pos = atomicAdd(&cursor[dst], 1);
            long long v = ((long long)__float_as_int(ea[i]) << 32) | (unsigned)ei[i];
            __builtin_nontemporal_store(v, (long long*)(csr + pos));
        }
    }
}

// ---------- K5: gather, one wave per node, lane = dim, 4-wide edge ILP ----------
__global__ __launch_bounds__(256) void gather_kernel(const int* __restrict__ offsets,
                                                     const int2* __restrict__ csr,
                                                     const bf16* __restrict__ xt,
                                                     const float* __restrict__ ewW,
                                                     const float* __restrict__ ewb,
                                                     const float* __restrict__ bias,
                                                     float* __restrict__ out,
                                                     int n_nodes) {
    const int d = threadIdx.x & 63;
    const int node = (blockIdx.x * blockDim.x + threadIdx.x) >> 6;
    if (node >= n_nodes) return;

    const float wd = ewW[d];
    const float bd = ewb[d];
    const int start = offsets[node];
    const int end = offsets[node + 1];

    float acc = 0.f;
    int k = start;
    for (; k + 4 <= end; k += 4) {
        int2 p0 = csr[k + 0];
        int2 p1 = csr[k + 1];
        int2 p2 = csr[k + 2];
        int2 p3 = csr[k + 3];
        float x0 = __bfloat162float(xt[(size_t)p0.x * 64 + d]);
        float x1 = __bfloat162float(xt[(size_t)p1.x * 64 + d]);
        float x2 = __bfloat162float(xt[(size_t)p2.x * 64 + d]);
        float x3 = __bfloat162float(xt[(size_t)p3.x * 64 + d]);
        float w0 = 1.f / (1.f + __expf(-(__int_as_float(p0.y) * wd + bd)));
        float w1 = 1.f / (1.f + __expf(-(__int_as_float(p1.y) * wd + bd)));
        float w2 = 1.f / (1.f + __expf(-(__int_as_float(p2.y) * wd + bd)));
        float w3 = 1.f / (1.f + __expf(-(__int_as_float(p3.y) * wd + bd)));
        acc = fmaf(x0, w0, acc);
        acc = fmaf(x1, w1, acc);
        acc = fmaf(x2, w2, acc);
        acc = fmaf(x3, w3, acc);
    }
    for (; k < end; ++k) {
        int2 p = csr[k];
        float xv = __bfloat162float(xt[(size_t)p.x * 64 + d]);
        float w = 1.f / (1.f + __expf(-(__int_as_float(p.y) * wd + bd)));
        acc = fmaf(xv, w, acc);
    }
    out[(size_t)node * 64 + d] = acc + bias[d];
}

// ---------- fallback (atomic scatter) ----------
__global__ __launch_bounds__(256) void init_out_kernel(float* __restrict__ out,
                                                       const float* __restrict__ bias,
                                                       int n_f4) {
    int i = blockIdx.x * blockDim.x + threadIdx.x;
    if (i >= n_f4) return;
    float4 b4 = reinterpret_cast<const float4*>(bias)[i & 15];
    reinterpret_cast<float4*>(out)[i] = b4;
}

__global__ __launch_bounds__(256) void edge_atomic_kernel(const int* __restrict__ ei,
                                                          const float* __restrict__ ea,
                                                          const bf16* __restrict__ xt,
                                                          const float* __restrict__ ewW,
                                                          const float* __restrict__ ewb,
                                                          float* __restrict__ out,
                                                          int n_edges) {
    const int gid = blockIdx.x * blockDim.x + threadIdx.x;
    const int d0 = (gid & 15) * 4;
    int e = gid >> 4;
    const int estride = (gridDim.x * blockDim.x) >> 4;
    for (; e < n_edges; e += estride) {
        const int src = ei[e];
        const int dst = ei[n_edges + e];
        const float a = ea[e];
        float xv0 = __bfloat162float(xt[(size_t)src * 64 + d0 + 0]);
        float xv1 = __bfloat162float(xt[(size_t)src * 64 + d0 + 1]);
        float xv2 = __bfloat162float(xt[(size_t)src * 64 + d0 + 2]);
        float xv3 = __bfloat162float(xt[(size_t)src * 64 + d0 + 3]);
        float w0 = 1.f / (1.f + __expf(-(a * ewW[d0 + 0] + ewb[d0 + 0])));
        float w1 = 1.f / (1.f + __expf(-(a * ewW[d0 + 1] + ewb[d0 + 1])));
        float w2 = 1.f / (1.f + __expf(-(a * ewW[d0 + 2] + ewb[d0 + 2])));
        float w3 = 1.f / (1.f + __expf(-(a * ewW[d0 + 3] + ewb[d0 + 3])));
        float* op = out + (size_t)dst * 64 + d0;
        unsafeAtomicAdd(op + 0, xv0 * w0);
        unsafeAtomicAdd(op + 1, xv1 * w1);
        unsafeAtomicAdd(op + 2, xv2 * w2);
        unsafeAtomicAdd(op + 3, xv3 * w3);
    }
}

extern "C" void kernel_launch(void* const* d_in, const int* in_sizes, int n_in,
                              void* d_out, int out_size, void* d_ws, size_t ws_size,
                              hipStream_t stream) {
    const float* x      = (const float*)d_in[0];
    const int*   ei     = (const int*)d_in[1];
    const float* ea     = (const float*)d_in[2];
    const float* weight = (const float*)d_in[3];
    const float* ewW    = (const float*)d_in[4];
    const float* ewb    = (const float*)d_in[5];
    const float* bias   = (const float*)d_in[6];
    float* out = (float*)d_out;

    const int n_nodes = in_sizes[0] / D;   // 100000
    const int n_edges = in_sizes[2];       // 1600000

    // workspace layout
    char* ws = (char*)d_ws;
    const size_t xt_bytes  = (size_t)n_nodes * D * sizeof(bf16);       // 12.8 MB
    const size_t off_off   = (xt_bytes + 7) & ~(size_t)7;
    const size_t off_bytes = ((size_t)n_nodes + 4) * sizeof(int);
    const size_t cur_off   = off_off + off_bytes;
    const size_t part_off  = cur_off + off_bytes;
    const size_t part_bytes = 512 * sizeof(int);
    size_t csr_off         = (part_off + part_bytes + 7) & ~(size_t)7;
    const size_t csr_bytes = (size_t)n_edges * sizeof(int2);           // 12.8 MB
    const size_t need      = csr_off + csr_bytes;

    bf16* xt     = (bf16*)(ws);
    int*  offs   = (int*)(ws + off_off);
    int*  cursor = (int*)(ws + cur_off);
    int*  parts  = (int*)(ws + part_off);
    int2* csr    = (int2*)(ws + csr_off);

    // counts := 0 (offs doubles as counts), then fused histogram + GEMM
    hipMemsetAsync(offs, 0, off_bytes, stream);
    gemm_count_kernel<<<1024, 256, 0, stream>>>(x, weight, ei, xt, offs, n_nodes, n_edges);

    if (ws_size < need) {
        int n_f4 = n_nodes * (D / 4);
        init_out_kernel<<<(n_f4 + 255) / 256, 256, 0, stream>>>(out, bias, n_f4);
        edge_atomic_kernel<<<4096, 256, 0, stream>>>(ei, ea, xt, ewW, ewb, out, n_edges);
        return;
    }

    const int nscan_blocks = (n_nodes + SCAN_B - 1) / SCAN_B;   // 391

    scan1_kernel<<<nscan_blocks, SCAN_B, 0, stream>>>(offs, offs, parts, n_nodes);
    scan23_kernel<<<nscan_blocks, SCAN_B, 0, stream>>>(offs, cursor, parts, n_nodes, n_edges);
    fill_kernel<<<(n_edges / 4 + 255) / 256, 256, 0, stream>>>(ei, ea, cursor, csr, n_edges);
    gather_kernel<<<(n_nodes * 64 + 255) / 256, 256, 0, stream>>>(offs, csr, xt, ewW, ewb, bias, out, n_nodes);
}

// Round 4
// 253.122 us; speedup vs baseline: 5.6212x; 1.2987x over previous
//
#include <hip/hip_runtime.h>
#include <hip/hip_bf16.h>
#include <math.h>

#define D 64
#define SCAN_B 256

typedef __hip_bfloat16 bf16;

// ---------- K1: fused dst-histogram (rank capture) + xt = x @ W (bf16 out) ----
// rank[e] = running index of edge e within its dst bucket. The atomic-with-
// return latency hides under 524K-thread TLP and the GEMM phase that follows.
__global__ __launch_bounds__(256) void gemm_count_kernel(
    const float* __restrict__ x, const float* __restrict__ W,
    const int* __restrict__ ei,
    bf16* __restrict__ xt, int* __restrict__ counts, int* __restrict__ rank,
    int n_nodes, int n_edges)
{
    const int gid = blockIdx.x * blockDim.x + threadIdx.x;
    const int nth = gridDim.x * blockDim.x;

    // phase A: histogram of dst, capturing per-edge rank
    for (int e = gid; e < n_edges; e += nth) {
        int dst = ei[n_edges + e];
        rank[e] = atomicAdd(&counts[dst], 1);
    }

    // phase B: one wave per row, lane d owns output column d
    const int d = threadIdx.x & 63;
    const int wid = gid >> 6;
    const int waves_total = nth >> 6;

    float wcol[64];
#pragma unroll
    for (int k = 0; k < 64; ++k) wcol[k] = W[k * 64 + d];

    for (int row = wid; row < n_nodes; row += waves_total) {
        const float4* xr = reinterpret_cast<const float4*>(x + (size_t)row * 64);
        float acc = 0.f;
#pragma unroll
        for (int kk = 0; kk < 16; ++kk) {
            float4 xv = xr[kk];
            acc = fmaf(xv.x, wcol[4 * kk + 0], acc);
            acc = fmaf(xv.y, wcol[4 * kk + 1], acc);
            acc = fmaf(xv.z, wcol[4 * kk + 2], acc);
            acc = fmaf(xv.w, wcol[4 * kk + 3], acc);
        }
        xt[(size_t)row * 64 + d] = __float2bfloat16(acc);
    }
}

// ---------- K2: block scan (exclusive) + block totals ----------
__global__ __launch_bounds__(SCAN_B) void scan1_kernel(const int* __restrict__ c,
                                                       int* __restrict__ excl,
                                                       int* __restrict__ partials,
                                                       int n) {
    __shared__ int s[SCAN_B];
    int i = blockIdx.x * SCAN_B + threadIdx.x;
    int v = (i < n) ? c[i] : 0;
    s[threadIdx.x] = v;
    __syncthreads();
    for (int off = 1; off < SCAN_B; off <<= 1) {
        int t = (threadIdx.x >= off) ? s[threadIdx.x - off] : 0;
        __syncthreads();
        s[threadIdx.x] += t;
        __syncthreads();
    }
    if (i < n) excl[i] = s[threadIdx.x] - v;
    if (threadIdx.x == SCAN_B - 1) partials[blockIdx.x] = s[SCAN_B - 1];
}

// ---------- K3: apply partials prefix (each block reduces its own prefix) ----
__global__ __launch_bounds__(SCAN_B) void scan23_kernel(int* __restrict__ offsets,
                                                        const int* __restrict__ partials,
                                                        int n, int n_edges) {
    __shared__ int red[SCAN_B];
    int psum = 0;
    for (int i = threadIdx.x; i < blockIdx.x; i += SCAN_B) psum += partials[i];
    red[threadIdx.x] = psum;
    __syncthreads();
    for (int off = SCAN_B / 2; off > 0; off >>= 1) {
        if (threadIdx.x < off) red[threadIdx.x] += red[threadIdx.x + off];
        __syncthreads();
    }
    int base = red[0];
    int i = blockIdx.x * SCAN_B + threadIdx.x;
    if (i < n) offsets[i] += base;
    if (blockIdx.x == 0 && threadIdx.x == 0) offsets[n] = n_edges;
}

// ---------- K4: CSR fill — NO atomics, pure dataflow scatter ----------
__global__ __launch_bounds__(256) void fill_kernel(const int* __restrict__ ei,
                                                   const float* __restrict__ ea,
                                                   const int* __restrict__ offs,
                                                   const int* __restrict__ rank,
                                                   int2* __restrict__ csr,
                                                   int n_edges) {
    int e = blockIdx.x * blockDim.x + threadIdx.x;
    if (e >= n_edges) return;
    int dst = ei[n_edges + e];
    int pos = offs[dst] + rank[e];
    long long v = ((long long)__float_as_int(ea[e]) << 32) | (unsigned)ei[e];
    __builtin_nontemporal_store(v, (long long*)(csr + pos));
}

// ---------- K5: gather, one wave per node, lane = dim, 4-wide edge ILP ------
__global__ __launch_bounds__(256) void gather_kernel(const int* __restrict__ offsets,
                                                     const int2* __restrict__ csr,
                                                     const bf16* __restrict__ xt,
                                                     const float* __restrict__ ewW,
                                                     const float* __restrict__ ewb,
                                                     const float* __restrict__ bias,
                                                     float* __restrict__ out,
                                                     int n_nodes) {
    const int d = threadIdx.x & 63;
    const int node = (blockIdx.x * blockDim.x + threadIdx.x) >> 6;
    if (node >= n_nodes) return;

    const float wd = ewW[d];
    const float bd = ewb[d];
    const int start = offsets[node];
    const int end = offsets[node + 1];

    float acc = 0.f;
    int k = start;
    for (; k + 4 <= end; k += 4) {
        long long q0 = __builtin_nontemporal_load((const long long*)(csr + k + 0));
        long long q1 = __builtin_nontemporal_load((const long long*)(csr + k + 1));
        long long q2 = __builtin_nontemporal_load((const long long*)(csr + k + 2));
        long long q3 = __builtin_nontemporal_load((const long long*)(csr + k + 3));
        int s0 = (int)(unsigned)q0, s1 = (int)(unsigned)q1;
        int s2 = (int)(unsigned)q2, s3 = (int)(unsigned)q3;
        float x0 = __bfloat162float(xt[(size_t)s0 * 64 + d]);
        float x1 = __bfloat162float(xt[(size_t)s1 * 64 + d]);
        float x2 = __bfloat162float(xt[(size_t)s2 * 64 + d]);
        float x3 = __bfloat162float(xt[(size_t)s3 * 64 + d]);
        float a0 = __int_as_float((int)(q0 >> 32));
        float a1 = __int_as_float((int)(q1 >> 32));
        float a2 = __int_as_float((int)(q2 >> 32));
        float a3 = __int_as_float((int)(q3 >> 32));
        float w0 = 1.f / (1.f + __expf(-(a0 * wd + bd)));
        float w1 = 1.f / (1.f + __expf(-(a1 * wd + bd)));
        float w2 = 1.f / (1.f + __expf(-(a2 * wd + bd)));
        float w3 = 1.f / (1.f + __expf(-(a3 * wd + bd)));
        acc = fmaf(x0, w0, acc);
        acc = fmaf(x1, w1, acc);
        acc = fmaf(x2, w2, acc);
        acc = fmaf(x3, w3, acc);
    }
    for (; k < end; ++k) {
        long long q = __builtin_nontemporal_load((const long long*)(csr + k));
        int s = (int)(unsigned)q;
        float xv = __bfloat162float(xt[(size_t)s * 64 + d]);
        float a = __int_as_float((int)(q >> 32));
        float w = 1.f / (1.f + __expf(-(a * wd + bd)));
        acc = fmaf(xv, w, acc);
    }
    float r = acc + bias[d];
    __builtin_nontemporal_store(r, out + (size_t)node * 64 + d);
}

// ---------- fallback (atomic scatter) ----------
__global__ __launch_bounds__(256) void init_out_kernel(float* __restrict__ out,
                                                       const float* __restrict__ bias,
                                                       int n_f4) {
    int i = blockIdx.x * blockDim.x + threadIdx.x;
    if (i >= n_f4) return;
    float4 b4 = reinterpret_cast<const float4*>(bias)[i & 15];
    reinterpret_cast<float4*>(out)[i] = b4;
}

__global__ __launch_bounds__(256) void edge_atomic_kernel(const int* __restrict__ ei,
                                                          const float* __restrict__ ea,
                                                          const bf16* __restrict__ xt,
                                                          const float* __restrict__ ewW,
                                                          const float* __restrict__ ewb,
                                                          float* __restrict__ out,
                                                          int n_edges) {
    const int gid = blockIdx.x * blockDim.x + threadIdx.x;
    const int d0 = (gid & 15) * 4;
    int e = gid >> 4;
    const int estride = (gridDim.x * blockDim.x) >> 4;
    for (; e < n_edges; e += estride) {
        const int src = ei[e];
        const int dst = ei[n_edges + e];
        const float a = ea[e];
        float xv0 = __bfloat162float(xt[(size_t)src * 64 + d0 + 0]);
        float xv1 = __bfloat162float(xt[(size_t)src * 64 + d0 + 1]);
        float xv2 = __bfloat162float(xt[(size_t)src * 64 + d0 + 2]);
        float xv3 = __bfloat162float(xt[(size_t)src * 64 + d0 + 3]);
        float w0 = 1.f / (1.f + __expf(-(a * ewW[d0 + 0] + ewb[d0 + 0])));
        float w1 = 1.f / (1.f + __expf(-(a * ewW[d0 + 1] + ewb[d0 + 1])));
        float w2 = 1.f / (1.f + __expf(-(a * ewW[d0 + 2] + ewb[d0 + 2])));
        float w3 = 1.f / (1.f + __expf(-(a * ewW[d0 + 3] + ewb[d0 + 3])));
        float* op = out + (size_t)dst * 64 + d0;
        unsafeAtomicAdd(op + 0, xv0 * w0);
        unsafeAtomicAdd(op + 1, xv1 * w1);
        unsafeAtomicAdd(op + 2, xv2 * w2);
        unsafeAtomicAdd(op + 3, xv3 * w3);
    }
}

extern "C" void kernel_launch(void* const* d_in, const int* in_sizes, int n_in,
                              void* d_out, int out_size, void* d_ws, size_t ws_size,
                              hipStream_t stream) {
    const float* x      = (const float*)d_in[0];
    const int*   ei     = (const int*)d_in[1];
    const float* ea     = (const float*)d_in[2];
    const float* weight = (const float*)d_in[3];
    const float* ewW    = (const float*)d_in[4];
    const float* ewb    = (const float*)d_in[5];
    const float* bias   = (const float*)d_in[6];
    float* out = (float*)d_out;

    const int n_nodes = in_sizes[0] / D;   // 100000
    const int n_edges = in_sizes[2];       // 1600000

    // workspace layout
    char* ws = (char*)d_ws;
    const size_t xt_bytes   = (size_t)n_nodes * D * sizeof(bf16);      // 12.8 MB
    const size_t off_off    = (xt_bytes + 7) & ~(size_t)7;
    const size_t off_bytes  = ((size_t)n_nodes + 4) * sizeof(int);
    const size_t part_off   = off_off + off_bytes;
    const size_t part_bytes = 512 * sizeof(int);
    const size_t rank_off   = part_off + part_bytes;
    const size_t rank_bytes = (size_t)n_edges * sizeof(int);           // 6.4 MB
    size_t csr_off          = (rank_off + rank_bytes + 7) & ~(size_t)7;
    const size_t csr_bytes  = (size_t)n_edges * sizeof(int2);          // 12.8 MB
    const size_t need       = csr_off + csr_bytes;                     // ~32.5 MB

    bf16* xt   = (bf16*)(ws);
    int*  offs = (int*)(ws + off_off);
    int*  parts= (int*)(ws + part_off);
    int*  rank = (int*)(ws + rank_off);
    int2* csr  = (int2*)(ws + csr_off);

    const bool have_ws = (ws_size >= need);

    // counts := 0 (offs doubles as counts), then fused histogram+rank + GEMM
    if (have_ws) {
        hipMemsetAsync(offs, 0, off_bytes, stream);
        gemm_count_kernel<<<2048, 256, 0, stream>>>(x, weight, ei, xt, offs, rank,
                                                    n_nodes, n_edges);

        const int nscan_blocks = (n_nodes + SCAN_B - 1) / SCAN_B;   // 391
        scan1_kernel<<<nscan_blocks, SCAN_B, 0, stream>>>(offs, offs, parts, n_nodes);
        scan23_kernel<<<nscan_blocks, SCAN_B, 0, stream>>>(offs, parts, n_nodes, n_edges);
        fill_kernel<<<(n_edges + 255) / 256, 256, 0, stream>>>(ei, ea, offs, rank, csr, n_edges);
        gather_kernel<<<(n_nodes * 64 + 255) / 256, 256, 0, stream>>>(offs, csr, xt, ewW, ewb,
                                                                      bias, out, n_nodes);
    } else {
        // fallback: atomic scatter path (needs only xt)
        gemm_count_kernel<<<2048, 256, 0, stream>>>(x, weight, ei, xt,
                                                    /*counts=*/nullptr, /*rank=*/nullptr,
                                                    n_nodes, 0 /* skip histogram */);
        int n_f4 = n_nodes * (D / 4);
        init_out_kernel<<<(n_f4 + 255) / 256, 256, 0, stream>>>(out, bias, n_f4);
        edge_atomic_kernel<<<4096, 256, 0, stream>>>(ei, ea, xt, ewW, ewb, out, n_edges);
    }
}